// Round 8
// baseline (222.617 us; speedup 1.0000x reference)
//
#include <hip/hip_runtime.h>
#include <hip/hip_bf16.h>

#define NN 4096
#define CAP 128   // max nnz per row tracked (binomial mean 41, sd 6.4)
#define KS 8      // k-splits for P-GEMM
#define PGB 1024  // pgemm blocks (128-thr, 2 wave-tiles each) at grid head

typedef __attribute__((ext_vector_type(8))) short bf16x8;
typedef __attribute__((ext_vector_type(4))) float f32x4;

__device__ __forceinline__ float lrelu(float v) { return v >= 0.f ? v : 0.2f * v; }

// fp32 -> bf16 bits, round-to-nearest-even (inputs are finite)
__device__ __forceinline__ ushort f2bu(float f) {
    unsigned u = __float_as_uint(f);
    return (ushort)((u + 0x7FFFu + ((u >> 16) & 1u)) >> 16);
}

// ---------------------------------------------------------------------------
// K1: xwA1=x@W1[0], xwB1=x@W1[1], xwA2=x@W2[0], xwB2=x@W2[1], v0=x@W0,
//     a/b attention vectors, Bt = (x@W0)^T as bf16 for the P-GEMM.
// ---------------------------------------------------------------------------
__global__ __launch_bounds__(256) void k_prep(
    const float* __restrict__ x,
    const float* __restrict__ W1, const float* __restrict__ W2,
    const float* __restrict__ W0,
    const float* __restrict__ att1, const float* __restrict__ att2,
    float* __restrict__ xwA1, float* __restrict__ xwB1,
    float* __restrict__ xwA2, float* __restrict__ xwB2,
    float* __restrict__ a1, float* __restrict__ b1,
    float* __restrict__ a2, float* __restrict__ b2,
    __hip_bfloat16* __restrict__ Bt)
{
    __shared__ float wl[5120];   // W1(2048) W2(2048) W0(1024)
    __shared__ float xs[256];    // 8 rows x 32
    const int t = threadIdx.x;
    for (int i = t; i < 2048; i += 256) { wl[i] = W1[i]; wl[2048 + i] = W2[i]; }
    for (int i = t; i < 1024; i += 256) wl[4096 + i] = W0[i];
    const int rowBase = blockIdx.x * 8;
    xs[t] = x[rowBase * 32 + t];
    __syncthreads();

    const int o = t & 31, r = t >> 5;
    const int row = rowBase + r;
    const float* xr = &xs[r * 32];
    float vA1 = 0.f, vB1 = 0.f, vA2 = 0.f, vB2 = 0.f, v0 = 0.f;
#pragma unroll
    for (int f = 0; f < 32; ++f) {
        const float xv = xr[f];
        vA1 += xv * wl[f * 32 + o];
        vB1 += xv * wl[1024 + f * 32 + o];
        vA2 += xv * wl[2048 + f * 32 + o];
        vB2 += xv * wl[3072 + f * 32 + o];
        v0  += xv * wl[4096 + f * 32 + o];
    }
    xwA1[row * 32 + o] = vA1;
    xwB1[row * 32 + o] = vB1;
    xwA2[row * 32 + o] = vA2;
    xwB2[row * 32 + o] = vB2;
    ((ushort*)Bt)[(size_t)o * NN + row] = f2bu(v0);

    float pa1 = vA1 * att1[o]      + vB1 * att1[32 + o];
    float pb1 = vA1 * att1[64 + o] + vB1 * att1[96 + o];
    float pa2 = vA2 * att2[o]      + vB2 * att2[32 + o];
    float pb2 = vA2 * att2[64 + o] + vB2 * att2[96 + o];
#pragma unroll
    for (int m = 1; m <= 16; m <<= 1) {
        pa1 += __shfl_xor(pa1, m); pb1 += __shfl_xor(pb1, m);
        pa2 += __shfl_xor(pa2, m); pb2 += __shfl_xor(pb2, m);
    }
    if (o == 0) { a1[row] = pa1; b1[row] = pb1; a2[row] = pa2; b2[row] = pb2; }
}

// ---------------------------------------------------------------------------
// K2 (k_fused): heterogeneous dispatch, 128-thread blocks.
//   blocks [0, PGB)        : pgemm body (per-wave MFMA, verified r4-r7).
//   blocks [PGB, PGB+2*NN) : scan body, one row per block. NEW this round:
//     single-pass LDS-ATOMIC compaction (consumers are order-invariant sums,
//     so slot order is free) -- deletes both ballot passes, the popcount
//     prefix, the cross-wave base exchange, and one barrier; y-gather widened
//     to 32-slot chunks (8 loads in flight). csrv is 32-padded with sentinels
//     (k_accum matches).
// ---------------------------------------------------------------------------
__global__ __launch_bounds__(128) void k_fused(
    const float* __restrict__ Ld, const float* __restrict__ Lu,
    const float* __restrict__ xwB1, const float* __restrict__ xwB2,
    const float* __restrict__ xwA1, const float* __restrict__ xwA2,
    const float* __restrict__ a1, const float* __restrict__ b1,
    const float* __restrict__ a2, const float* __restrict__ b2,
    int2* __restrict__ csrv, int* __restrict__ cntArr,
    float* __restrict__ u1, float* __restrict__ u2,
    const float* __restrict__ P, const ushort* __restrict__ Bt,
    float* __restrict__ partial)
{
    __shared__ int   sidx[CAP];
    __shared__ float sval[CAP];
    __shared__ float red[128];
    __shared__ float rpart[4];
    __shared__ int   lcnt;

    const int bid = blockIdx.x;
    const int t = threadIdx.x;
    const int lane = t & 63, w = t >> 6;      // w in {0,1}

    if (bid < PGB) {
        // ---------------- pgemm body (per-wave, verified r4-r7) ----------
        const int gw = bid * 2 + w;            // 0..2047
        const int mt = gw & 255;               // m-tile (16 rows)
        const int ks = gw >> 8;                // k-split 0..7
        const int m0 = mt * 16;
        const int r  = lane & 15;              // A row / B col within tile
        const int kq = lane >> 4;              // 8-k subchunk 0..3

        const float*  pa  = P  + (size_t)(m0 + r) * NN + ks * 512 + kq * 8;
        const ushort* pb0 = Bt + (size_t)r        * NN + ks * 512 + kq * 8;
        const ushort* pb1 = Bt + (size_t)(16 + r) * NN + ks * 512 + kq * 8;

        f32x4 acc0 = {0.f, 0.f, 0.f, 0.f};
        f32x4 acc1 = {0.f, 0.f, 0.f, 0.f};

#pragma unroll 4
        for (int kk = 0; kk < 16; ++kk) {
            const float4 a0  = *(const float4*)(pa + kk * 32);
            const float4 a1v = *(const float4*)(pa + kk * 32 + 4);
            const bf16x8 b0  = *(const bf16x8*)(pb0 + kk * 32);
            const bf16x8 b1v = *(const bf16x8*)(pb1 + kk * 32);
            bf16x8 a;
            a[0] = (short)f2bu(a0.x);  a[1] = (short)f2bu(a0.y);
            a[2] = (short)f2bu(a0.z);  a[3] = (short)f2bu(a0.w);
            a[4] = (short)f2bu(a1v.x); a[5] = (short)f2bu(a1v.y);
            a[6] = (short)f2bu(a1v.z); a[7] = (short)f2bu(a1v.w);
            acc0 = __builtin_amdgcn_mfma_f32_16x16x32_bf16(a, b0, acc0, 0, 0, 0);
            acc1 = __builtin_amdgcn_mfma_f32_16x16x32_bf16(a, b1v, acc1, 0, 0, 0);
        }

        // C/D layout: col = lane&15 (=r), row = (lane>>4)*4 + rr
        float* out = partial + ((size_t)ks * NN + m0 + kq * 4) * 32;
#pragma unroll
        for (int rr = 0; rr < 4; ++rr) {
            out[rr * 32 + r]      = acc0[rr];
            out[rr * 32 + 16 + r] = acc1[rr];
        }
        return;
    }

    // ---------------- scan body: one row, 128 threads ----------------
    const int sb  = bid - PGB;            // 0..8191
    const int br  = sb >> 12;             // 0..1
    const int row = sb & (NN - 1);
    const float* L   = br ? Lu : Ld;
    const float* xwB = br ? xwB2 : xwB1;
    const float* xwA = br ? xwA2 : xwA1;
    const float* aA  = br ? a2 : a1;
    const float* bA  = br ? b2 : b1;
    int2* csrB = csrv + ((size_t)br * NN + row) * CAP;
    float* u   = br ? u2 : u1;

    if (t == 0) lcnt = 0;
    __syncthreads();                          // trivially cheap: nothing in flight
    __builtin_amdgcn_sched_barrier(0);        // keep load issue below the barrier

    // issue the whole row: 8 float4 per lane, all in flight
    const float4* L4 = (const float4*)(L + (size_t)row * NN);
    float4 v[8];
#pragma unroll
    for (int j = 0; j < 8; ++j) v[j] = L4[j * 128 + t];

    // single-pass atomic compaction: no ballots, no prefix, no base chain
#pragma unroll
    for (int j = 0; j < 8; ++j) {
        const int c0 = (j * 128 + t) * 4;
        if (v[j].x != 0.f) { const int s = atomicAdd(&lcnt, 1); if (s < CAP) { sidx[s] = c0;     sval[s] = v[j].x; } }
        if (v[j].y != 0.f) { const int s = atomicAdd(&lcnt, 1); if (s < CAP) { sidx[s] = c0 + 1; sval[s] = v[j].y; } }
        if (v[j].z != 0.f) { const int s = atomicAdd(&lcnt, 1); if (s < CAP) { sidx[s] = c0 + 2; sval[s] = v[j].z; } }
        if (v[j].w != 0.f) { const int s = atomicAdd(&lcnt, 1); if (s < CAP) { sidx[s] = c0 + 3; sval[s] = v[j].w; } }
    }
    __syncthreads();

    const int cnt  = min(lcnt, CAP);
    const int cp32 = min((cnt + 31) & ~31, CAP);   // 32-padding (accum matches)
    // sentinel fill: thread t fills its OWN slot t (visible to others after
    // the rpart barrier below, which precedes all cross-thread reads).
    if (t >= cnt && t < cp32) { sidx[t] = 0; sval[t] = 0.f; }

    // --- softmax over the list: thread t handles slot t ---
    const float ai = aA[row];
    const int myidx = (t < cp32) ? sidx[t] : 0;    // own slot or compaction-barrier-covered
    const float e = (t < cnt) ? lrelu(ai + bA[myidx]) : -1e30f;
    float m = e;
#pragma unroll
    for (int mm = 1; mm <= 32; mm <<= 1) m = fmaxf(m, __shfl_xor(m, mm));
    if (lane == 0) rpart[w] = m;
    __syncthreads();                               // also publishes sentinels
    m = fmaxf(rpart[0], rpart[1]);
    const float wgt = (t < cnt) ? __expf(e - m) : 0.f;
    float ss = wgt;
#pragma unroll
    for (int mm = 1; mm <= 32; mm <<= 1) ss += __shfl_xor(ss, mm);
    if (lane == 0) rpart[2 + w] = ss;
    __syncthreads();
    const float ssum = rpart[2] + rpart[3];
    const float inv = (cnt > 0) ? 1.f / ssum : 0.f;
    if (t < cp32) { int2 eo; eo.x = myidx; eo.y = __float_as_int(wgt * inv); csrB[t] = eo; }
    if (t == 0) cntArr[br * NN + row] = cnt;

    // --- fused y-gather: 32-slot chunks, 8 loads in flight per thread ---
    const int o = t & 31, g = t >> 5;      // g in 0..3
    float acc = 0.f;
    for (int s0 = 0; s0 < cp32; s0 += 32) {
        float vv[8], uu[8];
#pragma unroll
        for (int q = 0; q < 8; ++q) {
            const int sl = s0 + 4 * q + g;
            vv[q] = sval[sl];
            uu[q] = xwB[(size_t)sidx[sl] * 32 + o];
        }
#pragma unroll
        for (int q = 0; q < 8; ++q) acc += vv[q] * uu[q];
    }
    red[t] = acc;
    __syncthreads();
    if (t < 32) {
        const float tot2 = red[t] + red[32 + t] + red[64 + t] + red[96 + t];
        u[(size_t)row * 32 + t] = tot2 + xwA[(size_t)row * 32 + t];
    }
}

// ---------------------------------------------------------------------------
// K3 (k_accum): wave per row. Weighted gather of U for both branches
// (weights pre-normalized, csrv 32-padded with sentinels), KS partials
// hoisted to the top so their streamed loads overlap the gather chains;
// gather processes 16-slot chunks per wave (8 loads in flight).
// ---------------------------------------------------------------------------
__global__ __launch_bounds__(256) void k_accum(
    const int2* __restrict__ csrv, const int* __restrict__ cntArr,
    const float* __restrict__ u1, const float* __restrict__ u2,
    const float* __restrict__ partial, float* __restrict__ outp)
{
    __shared__ int2 sle[4][2 * CAP];
    const int w = threadIdx.x >> 6, lane = threadIdx.x & 63;
    const int row = blockIdx.x * 4 + w;
    const int o = lane & 31, g = lane >> 5;
    int2* se = sle[w];

    // KS-partial fold first: 8 independent coalesced loads, issued early
    // (lanes >= 32 compute redundantly; only lane < 32 writes at the end)
    float total = 0.f;
#pragma unroll
    for (int p = 0; p < KS; ++p)
        total += partial[(size_t)p * NN * 32 + (size_t)row * 32 + o];

    int cp[2];
#pragma unroll
    for (int br = 0; br < 2; ++br) {
        const int cnt = cntArr[br * NN + row];
        cp[br] = min((cnt + 31) & ~31, CAP);     // 32-padding (scan matches)
        const int2* ci = csrv + ((size_t)br * NN + row) * CAP;
        if (lane < cp[br])      se[br * CAP + lane]      = ci[lane];
        if (lane + 64 < cp[br]) se[br * CAP + lane + 64] = ci[lane + 64];
    }
    // wave-private LDS segment; same-wave ordering

#pragma unroll
    for (int br = 0; br < 2; ++br) {
        const float* U = br ? u2 : u1;
        float acc = 0.f;
        const int nb = cp[br] >> 4;              // 16-slot chunks
        for (int j = 0; j < nb; ++j) {
            float wv[8], uv[8];
#pragma unroll
            for (int q = 0; q < 8; ++q) {
                const int2 e = se[br * CAP + 16 * j + 2 * q + g];
                wv[q] = __int_as_float(e.y);
                uv[q] = U[(size_t)e.x * 32 + o];
            }
#pragma unroll
            for (int q = 0; q < 8; ++q) acc += wv[q] * uv[q];
        }
        acc += __shfl_xor(acc, 32);
        total += acc;
    }

    if (lane < 32) outp[(size_t)row * 32 + o] = total;
}

extern "C" void kernel_launch(void* const* d_in, const int* in_sizes, int n_in,
                              void* d_out, int out_size, void* d_ws, size_t ws_size,
                              hipStream_t stream) {
    (void)in_sizes; (void)n_in; (void)out_size; (void)ws_size;
    const float* x    = (const float*)d_in[0];
    const float* Ld   = (const float*)d_in[1];
    const float* Lu   = (const float*)d_in[2];
    const float* P    = (const float*)d_in[3];
    const float* W1   = (const float*)d_in[4];
    const float* W2   = (const float*)d_in[5];
    const float* W0   = (const float*)d_in[6];
    const float* att1 = (const float*)d_in[7];
    const float* att2 = (const float*)d_in[8];

    float* ws = (float*)d_ws;
    float* xwA1 = ws;                 // 131072 each
    float* xwB1 = ws + 131072;
    float* xwA2 = ws + 262144;
    float* xwB2 = ws + 393216;
    float* u1   = ws + 524288;        // xwA + L@xwB (fused)
    float* u2   = ws + 655360;
    float* a1   = ws + 786432;        // 4096 each
    float* b1   = ws + 790528;
    float* a2   = ws + 794624;
    float* b2   = ws + 798720;
    float* partial = ws + 802816;           // KS*131072 floats = 4 MB
    __hip_bfloat16* Bt = (__hip_bfloat16*)(ws + 1851392);   // 131072 bf16
    int2* csrv = (int2*)(ws + 1916928);     // 2*4096*128 int2 = 8 MB
    int*  cnt  = (int*)(ws + 4014080);      // 8192 ints

    k_prep<<<512, 256, 0, stream>>>(x, W1, W2, W0, att1, att2,
                                    xwA1, xwB1, xwA2, xwB2, a1, b1, a2, b2, Bt);
    k_fused<<<PGB + 2 * NN, 128, 0, stream>>>(Ld, Lu, xwB1, xwB2, xwA1, xwA2,
                                              a1, b1, a2, b2, csrv, cnt, u1, u2,
                                              P, (const ushort*)Bt, partial);
    k_accum<<<NN / 4, 256, 0, stream>>>(csrv, cnt, u1, u2, partial,
                                        (float*)d_out);
}

// Round 9
// 220.930 us; speedup vs baseline: 1.0076x; 1.0076x over previous
//
#include <hip/hip_runtime.h>
#include <hip/hip_bf16.h>

#define NN 4096
#define CAP 128   // max nnz per row tracked (binomial mean 41, sd 6.4)
#define KS 8      // k-splits for P-GEMM
#define PGB 1024  // pgemm blocks (128-thr, 2 wave-tiles each) at grid head

typedef __attribute__((ext_vector_type(8))) short bf16x8;
typedef __attribute__((ext_vector_type(4))) float f32x4;

// global -> LDS direct copy, 16 B per lane (gfx950). LDS dest is wave-uniform
// base + lane*16 (linear); global src is per-lane.
typedef __attribute__((address_space(1))) const void gas_t;
typedef __attribute__((address_space(3))) void las_t;
#define GLOAD_LDS16(gsrc, ldst) \
    __builtin_amdgcn_global_load_lds((gas_t*)(gsrc), (las_t*)(ldst), 16, 0, 0)

__device__ __forceinline__ float lrelu(float v) { return v >= 0.f ? v : 0.2f * v; }

// fp32 -> bf16 bits, round-to-nearest-even (inputs are finite)
__device__ __forceinline__ ushort f2bu(float f) {
    unsigned u = __float_as_uint(f);
    return (ushort)((u + 0x7FFFu + ((u >> 16) & 1u)) >> 16);
}

// ---------------------------------------------------------------------------
// K1: xwA1=x@W1[0], xwB1=x@W1[1], xwA2=x@W2[0], xwB2=x@W2[1], v0=x@W0,
//     a/b attention vectors, Bt = (x@W0)^T as bf16 for the P-GEMM.
// ---------------------------------------------------------------------------
__global__ __launch_bounds__(256) void k_prep(
    const float* __restrict__ x,
    const float* __restrict__ W1, const float* __restrict__ W2,
    const float* __restrict__ W0,
    const float* __restrict__ att1, const float* __restrict__ att2,
    float* __restrict__ xwA1, float* __restrict__ xwB1,
    float* __restrict__ xwA2, float* __restrict__ xwB2,
    float* __restrict__ a1, float* __restrict__ b1,
    float* __restrict__ a2, float* __restrict__ b2,
    __hip_bfloat16* __restrict__ Bt)
{
    __shared__ float wl[5120];   // W1(2048) W2(2048) W0(1024)
    __shared__ float xs[256];    // 8 rows x 32
    const int t = threadIdx.x;
    for (int i = t; i < 2048; i += 256) { wl[i] = W1[i]; wl[2048 + i] = W2[i]; }
    for (int i = t; i < 1024; i += 256) wl[4096 + i] = W0[i];
    const int rowBase = blockIdx.x * 8;
    xs[t] = x[rowBase * 32 + t];
    __syncthreads();

    const int o = t & 31, r = t >> 5;
    const int row = rowBase + r;
    const float* xr = &xs[r * 32];
    float vA1 = 0.f, vB1 = 0.f, vA2 = 0.f, vB2 = 0.f, v0 = 0.f;
#pragma unroll
    for (int f = 0; f < 32; ++f) {
        const float xv = xr[f];
        vA1 += xv * wl[f * 32 + o];
        vB1 += xv * wl[1024 + f * 32 + o];
        vA2 += xv * wl[2048 + f * 32 + o];
        vB2 += xv * wl[3072 + f * 32 + o];
        v0  += xv * wl[4096 + f * 32 + o];
    }
    xwA1[row * 32 + o] = vA1;
    xwB1[row * 32 + o] = vB1;
    xwA2[row * 32 + o] = vA2;
    xwB2[row * 32 + o] = vB2;
    ((ushort*)Bt)[(size_t)o * NN + row] = f2bu(v0);

    float pa1 = vA1 * att1[o]      + vB1 * att1[32 + o];
    float pb1 = vA1 * att1[64 + o] + vB1 * att1[96 + o];
    float pa2 = vA2 * att2[o]      + vB2 * att2[32 + o];
    float pb2 = vA2 * att2[64 + o] + vB2 * att2[96 + o];
#pragma unroll
    for (int m = 1; m <= 16; m <<= 1) {
        pa1 += __shfl_xor(pa1, m); pb1 += __shfl_xor(pb1, m);
        pa2 += __shfl_xor(pa2, m); pb2 += __shfl_xor(pb2, m);
    }
    if (o == 0) { a1[row] = pa1; b1[row] = pb1; a2[row] = pa2; b2[row] = pb2; }
}

// ---------------------------------------------------------------------------
// K2 (k_fused): heterogeneous dispatch, 128-thread blocks.
//   blocks [0, PGB)        : pgemm body (per-wave MFMA, verified r4-r8).
//   blocks [PGB, PGB+2*NN) : scan body, one row per block. NEW this round:
//     the 16 KB row is staged via global_load_lds (fire-and-forget, zero
//     VGPR round-trip, one vmcnt(0) drain) instead of 8 float4 register
//     loads -- targets the measured load-issue wall (~1.5 TB/s effective
//     regardless of structure, VGPR-pressure-batched issue). All downstream
//     processing (atomic compaction, softmax, y-gather, 32-padded csrv)
//     is byte-identical to r8's verified code, reading the row from LDS.
// ---------------------------------------------------------------------------
__global__ __launch_bounds__(128) void k_fused(
    const float* __restrict__ Ld, const float* __restrict__ Lu,
    const float* __restrict__ xwB1, const float* __restrict__ xwB2,
    const float* __restrict__ xwA1, const float* __restrict__ xwA2,
    const float* __restrict__ a1, const float* __restrict__ b1,
    const float* __restrict__ a2, const float* __restrict__ b2,
    int2* __restrict__ csrv, int* __restrict__ cntArr,
    float* __restrict__ u1, float* __restrict__ u2,
    const float* __restrict__ P, const ushort* __restrict__ Bt,
    float* __restrict__ partial)
{
    __shared__ float4 lrow[NN / 4];   // 16 KB staged row
    __shared__ int   sidx[CAP];
    __shared__ float sval[CAP];
    __shared__ float red[128];
    __shared__ float rpart[4];
    __shared__ int   lcnt;

    const int bid = blockIdx.x;
    const int t = threadIdx.x;
    const int lane = t & 63, w = t >> 6;      // w in {0,1}

    if (bid < PGB) {
        // ---------------- pgemm body (per-wave, verified r4-r8) ----------
        const int gw = bid * 2 + w;            // 0..2047
        const int mt = gw & 255;               // m-tile (16 rows)
        const int ks = gw >> 8;                // k-split 0..7
        const int m0 = mt * 16;
        const int r  = lane & 15;              // A row / B col within tile
        const int kq = lane >> 4;              // 8-k subchunk 0..3

        const float*  pa  = P  + (size_t)(m0 + r) * NN + ks * 512 + kq * 8;
        const ushort* pb0 = Bt + (size_t)r        * NN + ks * 512 + kq * 8;
        const ushort* pb1 = Bt + (size_t)(16 + r) * NN + ks * 512 + kq * 8;

        f32x4 acc0 = {0.f, 0.f, 0.f, 0.f};
        f32x4 acc1 = {0.f, 0.f, 0.f, 0.f};

#pragma unroll 4
        for (int kk = 0; kk < 16; ++kk) {
            const float4 a0  = *(const float4*)(pa + kk * 32);
            const float4 a1v = *(const float4*)(pa + kk * 32 + 4);
            const bf16x8 b0  = *(const bf16x8*)(pb0 + kk * 32);
            const bf16x8 b1v = *(const bf16x8*)(pb1 + kk * 32);
            bf16x8 a;
            a[0] = (short)f2bu(a0.x);  a[1] = (short)f2bu(a0.y);
            a[2] = (short)f2bu(a0.z);  a[3] = (short)f2bu(a0.w);
            a[4] = (short)f2bu(a1v.x); a[5] = (short)f2bu(a1v.y);
            a[6] = (short)f2bu(a1v.z); a[7] = (short)f2bu(a1v.w);
            acc0 = __builtin_amdgcn_mfma_f32_16x16x32_bf16(a, b0, acc0, 0, 0, 0);
            acc1 = __builtin_amdgcn_mfma_f32_16x16x32_bf16(a, b1v, acc1, 0, 0, 0);
        }

        // C/D layout: col = lane&15 (=r), row = (lane>>4)*4 + rr
        float* out = partial + ((size_t)ks * NN + m0 + kq * 4) * 32;
#pragma unroll
        for (int rr = 0; rr < 4; ++rr) {
            out[rr * 32 + r]      = acc0[rr];
            out[rr * 32 + 16 + r] = acc1[rr];
        }
        return;
    }

    // ---------------- scan body: one row, 128 threads ----------------
    const int sb  = bid - PGB;            // 0..8191
    const int br  = sb >> 12;             // 0..1
    const int row = sb & (NN - 1);
    const float* L   = br ? Lu : Ld;
    const float* xwB = br ? xwB2 : xwB1;
    const float* xwA = br ? xwA2 : xwA1;
    const float* aA  = br ? a2 : a1;
    const float* bA  = br ? b2 : b1;
    int2* csrB = csrv + ((size_t)br * NN + row) * CAP;
    float* u   = br ? u2 : u1;

    if (t == 0) lcnt = 0;

    // stage the whole 16 KB row into LDS: 8 global_load_lds_dwordx4 per lane,
    // fire-and-forget (no VGPR writeback). LDS dest: wave-uniform base
    // (j*128 + w*64 float4s) + lane*16 -- linear, matches the load order.
    const float4* L4 = (const float4*)(L + (size_t)row * NN);
#pragma unroll
    for (int j = 0; j < 8; ++j) {
        GLOAD_LDS16(L4 + j * 128 + t, (char*)lrow + (j * 128 + w * 64) * 16);
    }
    asm volatile("s_waitcnt vmcnt(0)" ::: "memory");
    __syncthreads();   // row + lcnt visible to the whole block

    // single-pass atomic compaction from LDS (order-invariant consumers)
#pragma unroll
    for (int j = 0; j < 8; ++j) {
        const float4 v = lrow[j * 128 + t];
        const int c0 = (j * 128 + t) * 4;
        if (v.x != 0.f) { const int s = atomicAdd(&lcnt, 1); if (s < CAP) { sidx[s] = c0;     sval[s] = v.x; } }
        if (v.y != 0.f) { const int s = atomicAdd(&lcnt, 1); if (s < CAP) { sidx[s] = c0 + 1; sval[s] = v.y; } }
        if (v.z != 0.f) { const int s = atomicAdd(&lcnt, 1); if (s < CAP) { sidx[s] = c0 + 2; sval[s] = v.z; } }
        if (v.w != 0.f) { const int s = atomicAdd(&lcnt, 1); if (s < CAP) { sidx[s] = c0 + 3; sval[s] = v.w; } }
    }
    __syncthreads();

    const int cnt  = min(lcnt, CAP);
    const int cp32 = min((cnt + 31) & ~31, CAP);   // 32-padding (accum matches)
    // sentinel fill: thread t fills its OWN slot t (published by the barrier
    // below, which precedes all cross-thread reads of these slots).
    if (t >= cnt && t < cp32) { sidx[t] = 0; sval[t] = 0.f; }

    // --- softmax over the list: thread t handles slot t ---
    const float ai = aA[row];
    const int myidx = (t < cp32) ? sidx[t] : 0;
    const float e = (t < cnt) ? lrelu(ai + bA[myidx]) : -1e30f;
    float m = e;
#pragma unroll
    for (int mm = 1; mm <= 32; mm <<= 1) m = fmaxf(m, __shfl_xor(m, mm));
    if (lane == 0) rpart[w] = m;
    __syncthreads();                               // also publishes sentinels
    m = fmaxf(rpart[0], rpart[1]);
    const float wgt = (t < cnt) ? __expf(e - m) : 0.f;
    float ss = wgt;
#pragma unroll
    for (int mm = 1; mm <= 32; mm <<= 1) ss += __shfl_xor(ss, mm);
    if (lane == 0) rpart[2 + w] = ss;
    __syncthreads();
    const float ssum = rpart[2] + rpart[3];
    const float inv = (cnt > 0) ? 1.f / ssum : 0.f;
    if (t < cp32) { int2 eo; eo.x = myidx; eo.y = __float_as_int(wgt * inv); csrB[t] = eo; }
    if (t == 0) cntArr[br * NN + row] = cnt;

    // --- fused y-gather: 32-slot chunks, 8 loads in flight per thread ---
    const int o = t & 31, g = t >> 5;      // g in 0..3
    float acc = 0.f;
    for (int s0 = 0; s0 < cp32; s0 += 32) {
        float vv[8], uu[8];
#pragma unroll
        for (int q = 0; q < 8; ++q) {
            const int sl = s0 + 4 * q + g;
            vv[q] = sval[sl];
            uu[q] = xwB[(size_t)sidx[sl] * 32 + o];
        }
#pragma unroll
        for (int q = 0; q < 8; ++q) acc += vv[q] * uu[q];
    }
    red[t] = acc;
    __syncthreads();
    if (t < 32) {
        const float tot2 = red[t] + red[32 + t] + red[64 + t] + red[96 + t];
        u[(size_t)row * 32 + t] = tot2 + xwA[(size_t)row * 32 + t];
    }
}

// ---------------------------------------------------------------------------
// K3 (k_accum): wave per row. Weighted gather of U for both branches
// (weights pre-normalized, csrv 32-padded with sentinels), KS partials
// hoisted to the top so their streamed loads overlap the gather chains;
// gather processes 16-slot chunks per wave (8 loads in flight).
// ---------------------------------------------------------------------------
__global__ __launch_bounds__(256) void k_accum(
    const int2* __restrict__ csrv, const int* __restrict__ cntArr,
    const float* __restrict__ u1, const float* __restrict__ u2,
    const float* __restrict__ partial, float* __restrict__ outp)
{
    __shared__ int2 sle[4][2 * CAP];
    const int w = threadIdx.x >> 6, lane = threadIdx.x & 63;
    const int row = blockIdx.x * 4 + w;
    const int o = lane & 31, g = lane >> 5;
    int2* se = sle[w];

    // KS-partial fold first: 8 independent coalesced loads, issued early
    float total = 0.f;
#pragma unroll
    for (int p = 0; p < KS; ++p)
        total += partial[(size_t)p * NN * 32 + (size_t)row * 32 + o];

    int cp[2];
#pragma unroll
    for (int br = 0; br < 2; ++br) {
        const int cnt = cntArr[br * NN + row];
        cp[br] = min((cnt + 31) & ~31, CAP);     // 32-padding (scan matches)
        const int2* ci = csrv + ((size_t)br * NN + row) * CAP;
        if (lane < cp[br])      se[br * CAP + lane]      = ci[lane];
        if (lane + 64 < cp[br]) se[br * CAP + lane + 64] = ci[lane + 64];
    }
    // wave-private LDS segment; same-wave ordering

#pragma unroll
    for (int br = 0; br < 2; ++br) {
        const float* U = br ? u2 : u1;
        float acc = 0.f;
        const int nb = cp[br] >> 4;              // 16-slot chunks
        for (int j = 0; j < nb; ++j) {
            float wv[8], uv[8];
#pragma unroll
            for (int q = 0; q < 8; ++q) {
                const int2 e = se[br * CAP + 16 * j + 2 * q + g];
                wv[q] = __int_as_float(e.y);
                uv[q] = U[(size_t)e.x * 32 + o];
            }
#pragma unroll
            for (int q = 0; q < 8; ++q) acc += wv[q] * uv[q];
        }
        acc += __shfl_xor(acc, 32);
        total += acc;
    }

    if (lane < 32) outp[(size_t)row * 32 + o] = total;
}

extern "C" void kernel_launch(void* const* d_in, const int* in_sizes, int n_in,
                              void* d_out, int out_size, void* d_ws, size_t ws_size,
                              hipStream_t stream) {
    (void)in_sizes; (void)n_in; (void)out_size; (void)ws_size;
    const float* x    = (const float*)d_in[0];
    const float* Ld   = (const float*)d_in[1];
    const float* Lu   = (const float*)d_in[2];
    const float* P    = (const float*)d_in[3];
    const float* W1   = (const float*)d_in[4];
    const float* W2   = (const float*)d_in[5];
    const float* W0   = (const float*)d_in[6];
    const float* att1 = (const float*)d_in[7];
    const float* att2 = (const float*)d_in[8];

    float* ws = (float*)d_ws;
    float* xwA1 = ws;                 // 131072 each
    float* xwB1 = ws + 131072;
    float* xwA2 = ws + 262144;
    float* xwB2 = ws + 393216;
    float* u1   = ws + 524288;        // xwA + L@xwB (fused)
    float* u2   = ws + 655360;
    float* a1   = ws + 786432;        // 4096 each
    float* b1   = ws + 790528;
    float* a2   = ws + 794624;
    float* b2   = ws + 798720;
    float* partial = ws + 802816;           // KS*131072 floats = 4 MB
    __hip_bfloat16* Bt = (__hip_bfloat16*)(ws + 1851392);   // 131072 bf16
    int2* csrv = (int2*)(ws + 1916928);     // 2*4096*128 int2 = 8 MB
    int*  cnt  = (int*)(ws + 4014080);      // 8192 ints

    k_prep<<<512, 256, 0, stream>>>(x, W1, W2, W0, att1, att2,
                                    xwA1, xwB1, xwA2, xwB2, a1, b1, a2, b2, Bt);
    k_fused<<<PGB + 2 * NN, 128, 0, stream>>>(Ld, Lu, xwB1, xwB2, xwA1, xwA2,
                                              a1, b1, a2, b2, csrv, cnt, u1, u2,
                                              P, (const ushort*)Bt, partial);
    k_accum<<<NN / 4, 256, 0, stream>>>(csrv, cnt, u1, u2, partial,
                                        (float*)d_out);
}